// Round 10
// baseline (226.331 us; speedup 1.0000x reference)
//
#include <hip/hip_runtime.h>

// out[n,o] = sum_h silu(sum_w x[n,w]*W1[o,h,w] + b1[o,h]) * W2[o,h] + b2[o]
//   x: [131072, 64] f32, W1: [32,128,64] f32, b1: [32,128], W2: [32,128], b2: [32]
//
// R9 (resubmit; container failed twice — never measured):
// occupancy push. 512-thread blocks (8 waves x 32 rows), grid 1024 = 512 rb x 2 oh
// (oh = top bit so paired blocks share an XCD -> output lines merge in L2). LDS 34.8 KB
// double-buffer -> 4 blocks/CU x 8 waves = 32 waves/CU (100%); launch_bounds(512,8)
// caps VGPR at 64. Quad-rcp: the 4 activations of a stripe share one reciprocal
// (25% fewer transcendentals). Kept from R5/R8: frag-major scaled-bf16 W1 staged by
// global_load_lds, b1'/w2' in LDS, deferred stores, packed-f32 epilogue.
// Folding: W1'=-log2e*W1, b1'=-log2e*b1, w2'=-ln2*w2 so MFMA emits m=-z*log2e and
// silu(z)*w2 = m*rcp(1+exp2(m))*w2'.
#define NC    131072
#define WDIM  64
#define ODIM  32
#define HDIM  128
#define LOG2E 1.4426950408889634f
#define LN2   0.6931471805599453f

typedef __attribute__((ext_vector_type(8))) short bf16x8;   // MFMA A/B frag (4 VGPRs)
typedef __attribute__((ext_vector_type(4))) float f32x4;    // MFMA C/D frag
typedef __attribute__((ext_vector_type(4))) float flt4;
typedef __attribute__((ext_vector_type(2))) float f32x2;    // packed-f32 pair

__device__ __forceinline__ short f2bf(float f) {
    union { float f; unsigned u; } v; v.f = f;
    unsigned r = (v.u + 0x7FFFu + ((v.u >> 16) & 1u)) >> 16;   // RNE
    return (short)r;
}

// ---- prep: W1 -> frag-major bf16 (scaled); b1,w2 -> scaled f32, per-o contiguous ----
// w1f element (o, frag=t*2+k2, lane, i) = -log2e * W1[o][t*16+(lane&15)][k2*32+(lane>>4)*8+i]
// b1w2[o*256 + j]: j<128 -> -log2e*b1[o][j]; j>=128 -> -ln2*w2[o][j-128]
__global__ void prep_kernel(const float* __restrict__ W1, const float* __restrict__ b1,
                            const float* __restrict__ w2, short* __restrict__ w1f,
                            float* __restrict__ b1w2) {
    if (blockIdx.x < 128) {
        int tid  = blockIdx.x * 256 + threadIdx.x;   // 32768 threads
        int lane = tid & 63;
        int frag = (tid >> 6) & 15;
        int o    = tid >> 10;
        int t    = frag >> 1;
        int k2   = frag & 1;
        const float* src = W1 + ((size_t)(o * HDIM + t * 16 + (lane & 15)) * WDIM
                                 + k2 * 32 + (lane >> 4) * 8);
        bf16x8 v;
        #pragma unroll
        for (int i = 0; i < 8; ++i) v[i] = f2bf(src[i] * -LOG2E);
        *reinterpret_cast<bf16x8*>(w1f + (size_t)tid * 8) = v;
    } else {
        int idx = (blockIdx.x - 128) * 256 + threadIdx.x;    // 0..8191
        int o = idx >> 8, j = idx & 255;
        b1w2[idx] = (j < 128) ? b1[o * HDIM + j] * -LOG2E
                              : w2[o * HDIM + (j - 128)] * -LN2;
    }
}

__device__ __forceinline__ void async16(void* lds_dst, const void* g_src) {
    __builtin_amdgcn_global_load_lds(
        (const __attribute__((address_space(1))) unsigned int*)g_src,
        (__attribute__((address_space(3))) unsigned int*)lds_dst,
        16, 0, 0);
}

// LDS buffer layout (shorts): [16 frags x 512][b1' 256][w2' 256] = 8704 shorts = 17 KB
#define BUFSH 8704
#define OHALF 16

__global__ __launch_bounds__(512, 8)
void swr_main(const float* __restrict__ x, const short* __restrict__ w1f,
              const float* __restrict__ b1w2, const float* __restrict__ b2,
              float* __restrict__ out)
{
    __shared__ short w1lds[2 * BUFSH];           // 34 KB: double buffer, 17 KB per o
    const int tid  = threadIdx.x;
    const int lane = tid & 63;
    const int wid  = tid >> 6;                   // 0..7
    const int col  = lane & 15;
    const int kq   = lane >> 4;
    const int oh   = blockIdx.x >> 9;            // top bit: o-half (same-XCD pairing)
    const int rb   = blockIdx.x & 511;           // row-block: 256 rows
    const int obase = oh * OHALF;
    const size_t rowbase = (size_t)rb * 256 + (size_t)wid * 32;

    // x fragments (B operand: col = x-row, k = kq*8+i): 2 stripes x 2 k-halves
    bf16x8 xf[2][2];
    #pragma unroll
    for (int s = 0; s < 2; ++s) {
        #pragma unroll
        for (int k2 = 0; k2 < 2; ++k2) {
            const float* p = x + (rowbase + s * 16 + col) * WDIM + k2 * 32 + kq * 8;
            flt4 lo = *reinterpret_cast<const flt4*>(p);
            flt4 hi = *reinterpret_cast<const flt4*>(p + 4);
            bf16x8 a;
            a[0] = f2bf(lo[0]); a[1] = f2bf(lo[1]); a[2] = f2bf(lo[2]); a[3] = f2bf(lo[3]);
            a[4] = f2bf(hi[0]); a[5] = f2bf(hi[1]); a[6] = f2bf(hi[2]); a[7] = f2bf(hi[3]);
            xf[s][k2] = a;
        }
    }

    // stage first o into buffer 0 (8 waves stage 2 frags each; wave 0 also b1'/w2')
    #pragma unroll
    for (int f = 0; f < 2; ++f) {
        int frag = wid * 2 + f;
        async16(&w1lds[frag * 512], w1f + (size_t)obase * 8192 + frag * 512 + lane * 8);
    }
    if (wid == 0)
        async16(&w1lds[8192], b1w2 + (size_t)obase * 256 + lane * 4);
    __syncthreads();

    float* op0 = out + (rowbase + col) * ODIM;        // s=0 row for lanes 0..15
    float* op1 = out + (rowbase + 16 + col) * ODIM;   // s=1 row
    float pu0 = 0.f, pu1 = 0.f;

    #pragma unroll 1
    for (int o = 0; o < OHALF; ++o) {
        const int oabs = obase + o;
        const short* cur = &w1lds[(o & 1) * BUFSH];

        // flush previous-o results (issued ~1 full iteration before the next drain)
        if (o > 0 && lane < 16) { op0[oabs - 1] = pu0; op1[oabs - 1] = pu1; }

        if (o + 1 < OHALF) {                      // prefetch next o into other buffer
            const short* g = w1f + (size_t)(oabs + 1) * 8192;
            short* nb = &w1lds[((o + 1) & 1) * BUFSH];
            #pragma unroll
            for (int f = 0; f < 2; ++f) {
                int frag = wid * 2 + f;
                async16(nb + frag * 512, g + frag * 512 + lane * 8);
            }
            if (wid == 0)
                async16(nb + 8192, b1w2 + (size_t)(oabs + 1) * 256 + lane * 4);
        }
        const float b2o = b2[oabs];
        const flt4* bwl = reinterpret_cast<const flt4*>(cur + 8192);  // [0..31]=b1',[32..63]=w2'

        f32x2 part[2][2];
        #pragma unroll
        for (int s = 0; s < 2; ++s)
            #pragma unroll
            for (int p = 0; p < 2; ++p) part[s][p] = (f32x2){0.f, 0.f};

        #pragma unroll
        for (int t = 0; t < 8; ++t) {
            flt4 b1c = bwl[t * 4 + kq];                               // broadcast ds_read
            flt4 w2c = bwl[32 + t * 4 + kq];
            bf16x8 f0 = *reinterpret_cast<const bf16x8*>(cur + (t * 2 + 0) * 512 + lane * 8);
            bf16x8 f1 = *reinterpret_cast<const bf16x8*>(cur + (t * 2 + 1) * 512 + lane * 8);
            #pragma unroll
            for (int s = 0; s < 2; ++s) {
                f32x4 acc = __builtin_amdgcn_mfma_f32_16x16x32_bf16(
                                f0, xf[s][0], (f32x4){b1c[0], b1c[1], b1c[2], b1c[3]}, 0, 0, 0);
                acc = __builtin_amdgcn_mfma_f32_16x16x32_bf16(f1, xf[s][1], acc, 0, 0, 0);
                // D: col(lane&15)=x-row, row(kq*4+r) -> h = t*16+kq*4+r
                // Quad-rcp: the 4 acts of this stripe share one reciprocal.
                f32x2 mA  = { acc[0], acc[1] };                        // -z*log2e
                f32x2 mB  = { acc[2], acc[3] };
                f32x2 mwA = mA * (f32x2){ w2c[0], w2c[1] };            // off-chain
                f32x2 mwB = mB * (f32x2){ w2c[2], w2c[3] };
                f32x2 eA  = { __builtin_amdgcn_exp2f(mA.x),
                              __builtin_amdgcn_exp2f(mA.y) };          // exp(-z)
                f32x2 eB  = { __builtin_amdgcn_exp2f(mB.x),
                              __builtin_amdgcn_exp2f(mB.y) };
                f32x2 dA  = eA + (f32x2){1.f, 1.f};
                f32x2 dB  = eB + (f32x2){1.f, 1.f};
                float qA  = dA.x * dA.y;
                float qB  = dB.x * dB.y;
                float R   = __builtin_amdgcn_rcpf(qA * qB);            // 1/(qA*qB)
                float iqA = R * qB;                                    // 1/qA
                float iqB = R * qA;                                    // 1/qB
                f32x2 sA  = { iqA * dA.y, iqA * dA.x };                // sigmoid pair A
                f32x2 sB  = { iqB * dB.y, iqB * dB.x };                // sigmoid pair B
                part[s][0] = __builtin_elementwise_fma(mwA, sA, part[s][0]);
                part[s][1] = __builtin_elementwise_fma(mwB, sB, part[s][1]);
            }
        }

        // reduce 4 h's per lane (packed adds), then 4 kq groups (2 shfl_xor)
        {
            f32x2 u2 = part[0][0] + part[0][1];
            float u = u2.x + u2.y;
            u += __shfl_xor(u, 16);
            u += __shfl_xor(u, 32);
            pu0 = u + b2o;
        }
        {
            f32x2 u2 = part[1][0] + part[1][1];
            float u = u2.x + u2.y;
            u += __shfl_xor(u, 16);
            u += __shfl_xor(u, 32);
            pu1 = u + b2o;
        }
        __syncthreads();   // staging done + cur safe to overwrite; vmem queue is old
    }
    if (lane < 16) { op0[obase + OHALF - 1] = pu0; op1[obase + OHALF - 1] = pu1; }
}

extern "C" void kernel_launch(void* const* d_in, const int* in_sizes, int n_in,
                              void* d_out, int out_size, void* d_ws, size_t ws_size,
                              hipStream_t stream)
{
    const float* x  = (const float*)d_in[0];
    const float* W1 = (const float*)d_in[1];
    const float* b1 = (const float*)d_in[2];
    const float* w2 = (const float*)d_in[3];
    const float* b2 = (const float*)d_in[4];
    float* out = (float*)d_out;
    short* w1f  = (short*)d_ws;                              // 512 KB
    float* b1w2 = (float*)((char*)d_ws + 512 * 1024);        // 32 KB (32 o x 256 f32)

    hipLaunchKernelGGL(prep_kernel, dim3(160), dim3(256), 0, stream,
                       W1, b1, w2, w1f, b1w2);
    hipLaunchKernelGGL(swr_main, dim3(1024), dim3(512), 0, stream,
                       x, w1f, b1w2, b2, out);
}

// Round 11
// 217.800 us; speedup vs baseline: 1.0392x; 1.0392x over previous
//
#include <hip/hip_runtime.h>

// out[n,o] = sum_h silu(sum_w x[n,w]*W1[o,h,w] + b1[o,h]) * W2[o,h] + b2[o]
//   x: [131072, 64] f32, W1: [32,128,64] f32, b1: [32,128], W2: [32,128], b2: [32]
//
// R10: R8 skeleton (256 thr / 4 waves / 4 stripes / launch_bounds(256,4), 153 us
// proven) + from R9 only the validated pieces: quad-rcp epilogue, oh-as-top-bit
// (same-XCD pairing of the two halves of each output line). NEW: chunked stores —
// 4 o's accumulate in registers (flt4, static indexing via unrolled j-loop), one
// aligned float4 store per row per chunk, deferred to the next chunk's top.
// Kills the 4B-stride-128B scatter that caused 44-71 MB write amplification.
// Folding: W1'=-log2e*W1, b1'=-log2e*b1, w2'=-ln2*w2 so MFMA emits m=-z*log2e and
// silu(z)*w2 = m*rcp(1+exp2(m))*w2'.
#define NC    131072
#define WDIM  64
#define ODIM  32
#define HDIM  128
#define LOG2E 1.4426950408889634f
#define LN2   0.6931471805599453f

typedef __attribute__((ext_vector_type(8))) short bf16x8;   // MFMA A/B frag (4 VGPRs)
typedef __attribute__((ext_vector_type(4))) float f32x4;    // MFMA C/D frag
typedef __attribute__((ext_vector_type(4))) float flt4;
typedef __attribute__((ext_vector_type(2))) float f32x2;    // packed-f32 pair

__device__ __forceinline__ short f2bf(float f) {
    union { float f; unsigned u; } v; v.f = f;
    unsigned r = (v.u + 0x7FFFu + ((v.u >> 16) & 1u)) >> 16;   // RNE
    return (short)r;
}

// ---- prep: W1 -> frag-major bf16 (scaled); b1,w2 -> scaled f32, per-o contiguous ----
// w1f element (o, frag=t*2+k2, lane, i) = -log2e * W1[o][t*16+(lane&15)][k2*32+(lane>>4)*8+i]
// b1w2[o*256 + j]: j<128 -> -log2e*b1[o][j]; j>=128 -> -ln2*w2[o][j-128]
__global__ void prep_kernel(const float* __restrict__ W1, const float* __restrict__ b1,
                            const float* __restrict__ w2, short* __restrict__ w1f,
                            float* __restrict__ b1w2) {
    if (blockIdx.x < 128) {
        int tid  = blockIdx.x * 256 + threadIdx.x;   // 32768 threads
        int lane = tid & 63;
        int frag = (tid >> 6) & 15;
        int o    = tid >> 10;
        int t    = frag >> 1;
        int k2   = frag & 1;
        const float* src = W1 + ((size_t)(o * HDIM + t * 16 + (lane & 15)) * WDIM
                                 + k2 * 32 + (lane >> 4) * 8);
        bf16x8 v;
        #pragma unroll
        for (int i = 0; i < 8; ++i) v[i] = f2bf(src[i] * -LOG2E);
        *reinterpret_cast<bf16x8*>(w1f + (size_t)tid * 8) = v;
    } else {
        int idx = (blockIdx.x - 128) * 256 + threadIdx.x;    // 0..8191
        int o = idx >> 8, j = idx & 255;
        b1w2[idx] = (j < 128) ? b1[o * HDIM + j] * -LOG2E
                              : w2[o * HDIM + (j - 128)] * -LN2;
    }
}

__device__ __forceinline__ void async16(void* lds_dst, const void* g_src) {
    __builtin_amdgcn_global_load_lds(
        (const __attribute__((address_space(1))) unsigned int*)g_src,
        (__attribute__((address_space(3))) unsigned int*)lds_dst,
        16, 0, 0);
}

// LDS buffer layout (shorts): [16 frags x 512][b1' 256][w2' 256] = 8704 shorts = 17 KB
#define BUFSH 8704
#define OHALF 16

__global__ __launch_bounds__(256, 4)
void swr_main(const float* __restrict__ x, const short* __restrict__ w1f,
              const float* __restrict__ b1w2, const float* __restrict__ b2,
              float* __restrict__ out)
{
    __shared__ short w1lds[2 * BUFSH];           // 34 KB: double buffer, 17 KB per o
    const int tid  = threadIdx.x;
    const int lane = tid & 63;
    const int wid  = tid >> 6;                   // 0..3
    const int col  = lane & 15;
    const int kq   = lane >> 4;
    const int oh   = blockIdx.x >> 9;            // top bit: o-half (same-XCD pairing)
    const int rb   = blockIdx.x & 511;           // row-block: 256 rows
    const int obase = oh * OHALF;
    const size_t rowbase = (size_t)rb * 256 + (size_t)wid * 64;

    // x fragments (B operand: col = x-row, k = kq*8+i): 4 stripes x 2 k-halves
    bf16x8 xf[4][2];
    #pragma unroll
    for (int s = 0; s < 4; ++s) {
        #pragma unroll
        for (int k2 = 0; k2 < 2; ++k2) {
            const float* p = x + (rowbase + s * 16 + col) * WDIM + k2 * 32 + kq * 8;
            flt4 lo = *reinterpret_cast<const flt4*>(p);
            flt4 hi = *reinterpret_cast<const flt4*>(p + 4);
            bf16x8 a;
            a[0] = f2bf(lo[0]); a[1] = f2bf(lo[1]); a[2] = f2bf(lo[2]); a[3] = f2bf(lo[3]);
            a[4] = f2bf(hi[0]); a[5] = f2bf(hi[1]); a[6] = f2bf(hi[2]); a[7] = f2bf(hi[3]);
            xf[s][k2] = a;
        }
    }

    // stage first o into buffer 0 (4 waves stage 4 frags each; wave 0 also b1'/w2')
    #pragma unroll
    for (int f = 0; f < 4; ++f) {
        int frag = wid * 4 + f;
        async16(&w1lds[frag * 512], w1f + (size_t)obase * 8192 + frag * 512 + lane * 8);
    }
    if (wid == 0)
        async16(&w1lds[8192], b1w2 + (size_t)obase * 256 + lane * 4);
    __syncthreads();

    float* op[4];
    #pragma unroll
    for (int s = 0; s < 4; ++s)
        op[s] = out + (rowbase + s * 16 + col) * ODIM + obase;
    flt4 pu[4];                                   // 4 stripes x 4-o chunk accumulator

    #pragma unroll 1
    for (int oc = 0; oc < 4; ++oc) {
        // flush previous chunk: one aligned float4 per row (deferred past compute)
        if (oc > 0 && lane < 16) {
            #pragma unroll
            for (int s = 0; s < 4; ++s)
                *reinterpret_cast<flt4*>(op[s] + (oc - 1) * 4) = pu[s];
        }

        #pragma unroll
        for (int j = 0; j < 4; ++j) {             // static j: pu[s][j] stays in regs
            const int o = oc * 4 + j;
            const int oabs = obase + o;
            const short* cur = &w1lds[(j & 1) * BUFSH];

            if (o + 1 < OHALF) {                  // prefetch next o into other buffer
                const short* g = w1f + (size_t)(oabs + 1) * 8192;
                short* nb = &w1lds[((j + 1) & 1) * BUFSH];
                #pragma unroll
                for (int f = 0; f < 4; ++f) {
                    int frag = wid * 4 + f;
                    async16(nb + frag * 512, g + frag * 512 + lane * 8);
                }
                if (wid == 0)
                    async16(nb + 8192, b1w2 + (size_t)(oabs + 1) * 256 + lane * 4);
            }
            const float b2o = b2[oabs];
            const flt4* bwl = reinterpret_cast<const flt4*>(cur + 8192);

            f32x2 part[4][2];
            #pragma unroll
            for (int s = 0; s < 4; ++s)
                #pragma unroll
                for (int p = 0; p < 2; ++p) part[s][p] = (f32x2){0.f, 0.f};

            #pragma unroll
            for (int t = 0; t < 8; ++t) {
                flt4 b1c = bwl[t * 4 + kq];                           // broadcast ds_read
                flt4 w2c = bwl[32 + t * 4 + kq];
                bf16x8 f0 = *reinterpret_cast<const bf16x8*>(cur + (t * 2 + 0) * 512 + lane * 8);
                bf16x8 f1 = *reinterpret_cast<const bf16x8*>(cur + (t * 2 + 1) * 512 + lane * 8);
                #pragma unroll
                for (int s = 0; s < 4; ++s) {
                    f32x4 acc = __builtin_amdgcn_mfma_f32_16x16x32_bf16(
                                    f0, xf[s][0], (f32x4){b1c[0], b1c[1], b1c[2], b1c[3]}, 0, 0, 0);
                    acc = __builtin_amdgcn_mfma_f32_16x16x32_bf16(f1, xf[s][1], acc, 0, 0, 0);
                    // D: col(lane&15)=x-row, row(kq*4+r) -> h = t*16+kq*4+r
                    // Quad-rcp: 4 acts of this stripe share one reciprocal.
                    f32x2 mA  = { acc[0], acc[1] };                    // -z*log2e
                    f32x2 mB  = { acc[2], acc[3] };
                    f32x2 mwA = mA * (f32x2){ w2c[0], w2c[1] };        // off-chain
                    f32x2 mwB = mB * (f32x2){ w2c[2], w2c[3] };
                    f32x2 eA  = { __builtin_amdgcn_exp2f(mA.x),
                                  __builtin_amdgcn_exp2f(mA.y) };      // exp(-z)
                    f32x2 eB  = { __builtin_amdgcn_exp2f(mB.x),
                                  __builtin_amdgcn_exp2f(mB.y) };
                    f32x2 dA  = eA + (f32x2){1.f, 1.f};
                    f32x2 dB  = eB + (f32x2){1.f, 1.f};
                    float qA  = dA.x * dA.y;
                    float qB  = dB.x * dB.y;
                    float R   = __builtin_amdgcn_rcpf(qA * qB);        // 1/(qA*qB)
                    float iqA = R * qB;                                // 1/qA
                    float iqB = R * qA;                                // 1/qB
                    f32x2 sA  = { iqA * dA.y, iqA * dA.x };            // sigmoids A
                    f32x2 sB  = { iqB * dB.y, iqB * dB.x };            // sigmoids B
                    part[s][0] = __builtin_elementwise_fma(mwA, sA, part[s][0]);
                    part[s][1] = __builtin_elementwise_fma(mwB, sB, part[s][1]);
                }
            }

            // reduce 4 h's per lane (packed adds), then 4 kq groups (2 shfl_xor)
            #pragma unroll
            for (int s = 0; s < 4; ++s) {
                f32x2 u2 = part[s][0] + part[s][1];
                float u = u2.x + u2.y;
                u += __shfl_xor(u, 16);
                u += __shfl_xor(u, 32);
                pu[s][j] = u + b2o;               // static index (j unrolled)
            }
            __syncthreads();   // staging done + cur safe to overwrite
        }
    }
    // final flush (chunk 3)
    if (lane < 16) {
        #pragma unroll
        for (int s = 0; s < 4; ++s)
            *reinterpret_cast<flt4*>(op[s] + 12) = pu[s];
    }
}

extern "C" void kernel_launch(void* const* d_in, const int* in_sizes, int n_in,
                              void* d_out, int out_size, void* d_ws, size_t ws_size,
                              hipStream_t stream)
{
    const float* x  = (const float*)d_in[0];
    const float* W1 = (const float*)d_in[1];
    const float* b1 = (const float*)d_in[2];
    const float* w2 = (const float*)d_in[3];
    const float* b2 = (const float*)d_in[4];
    float* out = (float*)d_out;
    short* w1f  = (short*)d_ws;                              // 512 KB
    float* b1w2 = (float*)((char*)d_ws + 512 * 1024);        // 32 KB (32 o x 256 f32)

    hipLaunchKernelGGL(prep_kernel, dim3(160), dim3(256), 0, stream,
                       W1, b1, w2, w1f, b1w2);
    hipLaunchKernelGGL(swr_main, dim3(1024), dim3(256), 0, stream,
                       x, w1f, b1w2, b2, out);
}